// Round 11
// baseline (468.119 us; speedup 1.0000x reference)
//
#include <hip/hip_runtime.h>
#include <hip/hip_bf16.h>
#include <cstdint>

#define N_NODES 50000
#define N_EDGES 800000

// ---------------------------------------------------------------------------
// feat = X @ W  and el/er = per-head attention dots.
// SGPR-X design: 256 thr = 4 waves; wave owns 8 rows x DOUT cols (CPL=DOUT/64
// cols per lane). Row index is wave-uniform -> readfirstlane -> X reads become
// s_load (scalar pipe), freeing the LDS pipe (the measured bottleneck: R10 did
// 10 b128/k-quad/wave -> 4 waves x 120cyc vs 128cyc FMA). W packed in LDS as
// wl[k2][cg][2k x CPL]: ONE ds_read_b128 per k-pair feeds 32 FMA instrs.
template<int DIN, int DOUT, int F>
__global__ __launch_bounds__(256) void gemm_attn(
    const float* __restrict__ X, const float* __restrict__ W,
    const float* __restrict__ al, const float* __restrict__ ar,
    float* __restrict__ feat, float* __restrict__ el, float* __restrict__ er, int N)
{
    constexpr int KP  = 64;             // k-phase size
    constexpr int NPH = DIN / KP;
    constexpr int K2  = KP / 2;
    constexpr int CPL = DOUT / 64;      // cols per lane (2 for 128, 1 for 64)
    constexpr int H   = DOUT / F;
    constexpr int NF4 = KP * (DOUT / 4) / 256;  // W float4 loads per thread

    __shared__ float wl[K2][64][2 * CPL];

    const int tid  = threadIdx.x;
    const int wid  = tid >> 6;
    const int lane = tid & 63;
    const int row0 = blockIdx.x * 32 + wid * 8;

    // wave-uniform row base pointers -> SGPR pairs
    const float* Xr[8];
#pragma unroll
    for (int r = 0; r < 8; ++r) {
        int rr = row0 + r;
        rr = (rr < N) ? rr : (N - 1);
        Xr[r] = X + (size_t)__builtin_amdgcn_readfirstlane(rr) * DIN;
    }

    float acc[8][CPL] = {};

    for (int ph = 0; ph < NPH; ++ph) {
        __syncthreads();
        // stage W phase: KP rows x DOUT cols, packed for b128-per-k-pair reads
#pragma unroll
        for (int i = 0; i < NF4; ++i) {
            int s = tid + i * 256;
            int k = s / (DOUT / 4), c4 = (s % (DOUT / 4)) * 4;
            const float4 v = *reinterpret_cast<const float4*>(
                &W[(size_t)(ph * KP + k) * DOUT + c4]);
            int k2 = k >> 1;
            if constexpr (CPL == 2) {
                int sub = (k & 1) * 2;
                *reinterpret_cast<float2*>(&wl[k2][c4 >> 1][sub]) = make_float2(v.x, v.y);
                *reinterpret_cast<float2*>(&wl[k2][(c4 >> 1) + 1][sub]) = make_float2(v.z, v.w);
            } else {
                int sub = k & 1;
                wl[k2][c4 + 0][sub] = v.x;
                wl[k2][c4 + 1][sub] = v.y;
                wl[k2][c4 + 2][sub] = v.z;
                wl[k2][c4 + 3][sub] = v.w;
            }
        }
        __syncthreads();

        const int kb = ph * KP;
#pragma unroll 2
        for (int k2 = 0; k2 < K2; ++k2) {
            float wv[2 * CPL];
            if constexpr (CPL == 2)
                *reinterpret_cast<float4*>(wv) =
                    *reinterpret_cast<const float4*>(&wl[k2][lane][0]);
            else
                *reinterpret_cast<float2*>(wv) =
                    *reinterpret_cast<const float2*>(&wl[k2][lane][0]);
#pragma unroll
            for (int r = 0; r < 8; ++r) {
                const float xa = Xr[r][kb + 2 * k2];       // s_load (uniform)
                const float xb = Xr[r][kb + 2 * k2 + 1];   // s_load (uniform)
                if constexpr (CPL == 2) {
                    acc[r][0] = fmaf(xa, wv[0], acc[r][0]);
                    acc[r][1] = fmaf(xa, wv[1], acc[r][1]);
                    acc[r][0] = fmaf(xb, wv[2], acc[r][0]);
                    acc[r][1] = fmaf(xb, wv[3], acc[r][1]);
                } else {
                    acc[r][0] = fmaf(xa, wv[0], acc[r][0]);
                    acc[r][0] = fmaf(xb, wv[1], acc[r][0]);
                }
            }
        }
    }

    // ---- attention dots: per-lane partial + shfl reduce over LPH lanes ----
    constexpr int LPH = F / CPL;        // lanes per head: 8 (L0/L1), 64 (L2)
    float alv[CPL], arv[CPL];
#pragma unroll
    for (int c = 0; c < CPL; ++c) {
        alv[c] = al[CPL * lane + c];
        arv[c] = ar[CPL * lane + c];
    }

#pragma unroll
    for (int r = 0; r < 8; ++r) {
        int row = row0 + r;
        float pl = 0.f, pr = 0.f;
#pragma unroll
        for (int c = 0; c < CPL; ++c) {
            pl = fmaf(acc[r][c], alv[c], pl);
            pr = fmaf(acc[r][c], arv[c], pr);
        }
#pragma unroll
        for (int off = 1; off < LPH; off <<= 1) {
            pl += __shfl_xor(pl, off);
            pr += __shfl_xor(pr, off);
        }
        if (row < N && (lane & (LPH - 1)) == 0) {
            int h = (CPL * lane) / F;
            el[(size_t)row * H + h] = pl;
            er[(size_t)row * H + h] = pr;
        }
        if (row < N) {
            if constexpr (CPL == 2)
                *reinterpret_cast<float2*>(&feat[(size_t)row * DOUT + 2 * lane]) =
                    make_float2(acc[r][0], acc[r][1]);
            else
                feat[(size_t)row * DOUT + lane] = acc[r][0];
        }
    }
}

// ---------------------------------------------------------------------------
// CSR build (dst-sorted), shared by all 3 layers
__global__ void zero_ints(int* __restrict__ a, int n)
{
    int i = blockIdx.x * blockDim.x + threadIdx.x;
    if (i < n) a[i] = 0;
}

__global__ void hist_deg(const int* __restrict__ dst, int* __restrict__ deg)
{
    int e = blockIdx.x * blockDim.x + threadIdx.x;
    if (e < N_EDGES) atomicAdd(&deg[dst[e]], 1);
}

__global__ __launch_bounds__(1024) void scan_offsets(
    const int* __restrict__ deg, int* __restrict__ offs, int n)
{
    __shared__ int wtot[16], wincl[16];
    __shared__ int carry_s;
    const int tid = threadIdx.x;
    const int lane = tid & 63, wid = tid >> 6;
    if (tid == 0) carry_s = 0;
    __syncthreads();
    for (int base = 0; base < n; base += 1024) {
        int i = base + tid;
        int v = (i < n) ? deg[i] : 0;
        int x = v;
#pragma unroll
        for (int off = 1; off < 64; off <<= 1) {
            int t = __shfl_up(x, off);
            if (lane >= off) x += t;
        }
        if (lane == 63) wtot[wid] = x;
        __syncthreads();
        if (tid < 16) {
            int wx = wtot[tid];
#pragma unroll
            for (int off = 1; off < 16; off <<= 1) {
                int t = __shfl_up(wx, off);
                if (tid >= off) wx += t;
            }
            wincl[tid] = wx;
        }
        __syncthreads();
        int waveExcl = (wid == 0) ? 0 : wincl[wid - 1];
        if (i < n) offs[i] = carry_s + waveExcl + (x - v);
        int total = wincl[15];
        __syncthreads();
        if (tid == 0) carry_s += total;
        __syncthreads();
    }
    if (threadIdx.x == 0) offs[n] = carry_s;
}

__global__ void build_csr(const int* __restrict__ src, const int* __restrict__ dst,
                          const int* __restrict__ offs, int* __restrict__ cursor,
                          int* __restrict__ csr_src)
{
    int e = blockIdx.x * blockDim.x + threadIdx.x;
    if (e >= N_EDGES) return;
    int d = dst[e];
    int p = offs[d] + atomicAdd(&cursor[d], 1);
    csr_src[p] = src[e];
}

// ---------------------------------------------------------------------------
// Fused softmax + aggregation per dst node. One wave per node.
// [R10: at ~3.2-3.3 TB/s L2-fill plateau across 4 structural variants --
//  per-XCD fabric ceiling for random 512B gathers; ~1.2x traffic floor.]
template<int H, int F, bool ACT>
__global__ __launch_bounds__(256) void node_flash_agg(
    const int* __restrict__ offs, const int* __restrict__ csr_src,
    const float* __restrict__ el, const float* __restrict__ er,
    const float* __restrict__ feat, const float* __restrict__ bias,
    float* __restrict__ out, int N)
{
    constexpr int D = H * F;
    constexpr int CPT = D / 64;             // 2 or 1
    constexpr int EPC = 64 / H;             // 8 or 64
    constexpr int MAXCH = (H == 8) ? 4 : 1; // fast path: deg<=32 / 64
    constexpr int SB = 8;
    constexpr int NB = MAXCH * EPC / SB;    // feat batches (4 or 8)

    const int wid = threadIdx.x >> 6;
    const int lane = threadIdx.x & 63;
    const int n = blockIdx.x * 4 + wid;
    if (n >= N) return;

    const int beg = offs[n];
    const int deg = offs[n + 1] - beg;

    const int comp0 = CPT * lane;
    const int myhead = comp0 / F;

    if (deg == 0) {
#pragma unroll
        for (int c = 0; c < CPT; ++c) {
            float v = bias[comp0 + c];
            if (ACT) v = (v > 0.f) ? v : expm1f(v);
            out[(size_t)n * D + comp0 + c] = v;
        }
        return;
    }

    const int h = lane % H;
    const int esub = lane / H;
    const float erd = er[(size_t)n * H + h];

    float acc[CPT];
#pragma unroll
    for (int c = 0; c < CPT; ++c) acc[c] = 0.f;

    if (deg <= MAXCH * EPC) {
        // ================= fast path =================
        const int nch = (deg + EPC - 1) / EPC;      // wave-uniform
        int sreg[MAXCH];
        float ex[MAXCH];

#pragma unroll
        for (int j = 0; j < MAXCH; ++j) {
            if (j < nch) {
                sreg[j] = csr_src[beg + min(j * EPC + esub, deg - 1)];
                ex[j] = el[(size_t)sreg[j] * H + h];
            }
        }
        float m = -1e30f;
#pragma unroll
        for (int j = 0; j < MAXCH; ++j) {
            if (j < nch) {
                float v = ex[j] + erd;
                v = (v > 0.f) ? v : 0.2f * v;       // leaky_relu 0.2
                v = (j * EPC + esub < deg) ? v : -1e30f;
                ex[j] = v;
                m = fmaxf(m, v);
            }
        }
#pragma unroll
        for (int off = H; off < 64; off <<= 1)
            m = fmaxf(m, __shfl_xor(m, off));
        float s = 0.f;
#pragma unroll
        for (int j = 0; j < MAXCH; ++j) {
            if (j < nch) { ex[j] = __expf(ex[j] - m); s += ex[j]; }
        }
#pragma unroll
        for (int off = H; off < 64; off <<= 1)
            s += __shfl_xor(s, off);
        const float inv = 1.f / s;
#pragma unroll
        for (int j = 0; j < MAXCH; ++j)
            if (j < nch) ex[j] *= inv;              // normalize upfront

        // ---- weighting: 2-deep ping-pong pipelined gather ----
        float fvA[SB][CPT], fvB[SB][CPT];
        auto ldb = [&](int j, int g, float (&fv)[SB][CPT]) {
#pragma unroll
            for (int ii = 0; ii < SB; ++ii) {
                int sl = __shfl(sreg[j], (g + ii) * H);
                if constexpr (CPT == 2) {
                    float2 t = *reinterpret_cast<const float2*>(
                        &feat[(size_t)sl * D + comp0]);
                    fv[ii][0] = t.x; fv[ii][1] = t.y;
                } else {
                    fv[ii][0] = feat[(size_t)sl * D + comp0];
                }
            }
        };
        auto fmab = [&](int j, int g, float (&fv)[SB][CPT]) {
#pragma unroll
            for (int ii = 0; ii < SB; ++ii) {
                float exb = __shfl(ex[j], (g + ii) * H + myhead);
#pragma unroll
                for (int c = 0; c < CPT; ++c)
                    acc[c] = fmaf(fv[ii][c], exb, acc[c]);
            }
        };

        ldb(0, 0, fvA);                             // prologue
#pragma unroll
        for (int b = 0; b < NB; ++b) {
            if (b * SB < deg) {
                if ((b + 1) * SB < deg) {           // prefetch next batch
                    const int jn = ((b + 1) * SB) / EPC;
                    const int gn = ((b + 1) * SB) % EPC;
                    if ((b & 1) == 0) ldb(jn, gn, fvB);
                    else              ldb(jn, gn, fvA);
                }
                const int j = (b * SB) / EPC;
                const int g = (b * SB) % EPC;
                if ((b & 1) == 0) fmab(j, g, fvA);
                else              fmab(j, g, fvB);
            }
        }
#pragma unroll
        for (int c = 0; c < CPT; ++c) {
            float v = acc[c] + bias[comp0 + c];
            if (ACT) v = (v > 0.f) ? v : expm1f(v);
            acc[c] = v;
        }
    } else {
        // ================= generic online fallback =================
        float m_run = -1e30f, s_run = 0.f;
        int sN = csr_src[beg + min(esub, deg - 1)];
        float elN = el[(size_t)sN * H + h];

        for (int base = 0; base < deg; base += EPC) {
            const int s_mine = sN;
            const float elv = elN;
            const int nb = base + EPC;
            if (nb < deg) {
                sN = csr_src[beg + min(nb + esub, deg - 1)];
                elN = el[(size_t)sN * H + h];
            }
            float v = elv + erd;
            v = (v > 0.f) ? v : 0.2f * v;
            float logit = (base + esub < deg) ? v : -1e30f;

            float cmax = logit;
#pragma unroll
            for (int off = H; off < 64; off <<= 1)
                cmax = fmaxf(cmax, __shfl_xor(cmax, off));
            float nm = fmaxf(m_run, cmax);
            float scale = __expf(m_run - nm);
            float ex = __expf(logit - nm);
            float csum = ex;
#pragma unroll
            for (int off = H; off < 64; off <<= 1)
                csum += __shfl_xor(csum, off);
            s_run = s_run * scale + csum;
            m_run = nm;

            const float sc = __shfl(scale, myhead);
#pragma unroll
            for (int c = 0; c < CPT; ++c) acc[c] *= sc;

            const int active = min(EPC, deg - base);
            for (int g = 0; g < active; g += SB) {
                float fv[SB][CPT];
#pragma unroll
                for (int ii = 0; ii < SB; ++ii) {
                    int sl = __shfl(s_mine, (g + ii) * H);
                    if constexpr (CPT == 2) {
                        float2 t = *reinterpret_cast<const float2*>(
                            &feat[(size_t)sl * D + comp0]);
                        fv[ii][0] = t.x; fv[ii][1] = t.y;
                    } else {
                        fv[ii][0] = feat[(size_t)sl * D + comp0];
                    }
                }
#pragma unroll
                for (int ii = 0; ii < SB; ++ii) {
                    float exb = __shfl(ex, (g + ii) * H + myhead);
#pragma unroll
                    for (int c = 0; c < CPT; ++c)
                        acc[c] = fmaf(fv[ii][c], exb, acc[c]);
                }
            }
        }
        const float invb = __shfl(1.f / s_run, myhead);
#pragma unroll
        for (int c = 0; c < CPT; ++c) {
            float v = acc[c] * invb + bias[comp0 + c];
            if (ACT) v = (v > 0.f) ? v : expm1f(v);
            acc[c] = v;
        }
    }

    if constexpr (CPT == 2) {
        *reinterpret_cast<float2*>(&out[(size_t)n * D + comp0]) =
            make_float2(acc[0], acc[1]);
    } else {
        out[(size_t)n * D + comp0] = acc[0];
    }
}

// ---------------------------------------------------------------------------
extern "C" void kernel_launch(void* const* d_in, const int* in_sizes, int n_in,
                              void* d_out, int out_size, void* d_ws, size_t ws_size,
                              hipStream_t stream)
{
    const float* x   = (const float*)d_in[0];
    const int*   src = (const int*)d_in[1];
    const int*   dst = (const int*)d_in[2];
    const float* W0  = (const float*)d_in[3];
    const float* al0 = (const float*)d_in[4];
    const float* ar0 = (const float*)d_in[5];
    const float* b0  = (const float*)d_in[6];
    const float* W1  = (const float*)d_in[7];
    const float* al1 = (const float*)d_in[8];
    const float* ar1 = (const float*)d_in[9];
    const float* b1  = (const float*)d_in[10];
    const float* W2  = (const float*)d_in[11];
    const float* al2 = (const float*)d_in[12];
    const float* ar2 = (const float*)d_in[13];
    const float* b2  = (const float*)d_in[14];
    float* out = (float*)d_out;

    const int N = N_NODES, E = N_EDGES;

    float* ws   = (float*)d_ws;
    float* feat = ws;                         // N*128
    float* hbuf = feat + (size_t)N * 128;     // N*128
    float* elb  = hbuf + (size_t)N * 128;     // N*8
    float* erb  = elb + (size_t)N * 8;        // N*8
    int* ibase   = (int*)(erb + (size_t)N * 8);
    int* deg     = ibase;                     // N
    int* cursor  = deg + N;                   // N
    int* offs    = cursor + N;                // N+1
    int* csr_src = offs + N + 1;              // E

    const int TB = 256;
    const int gb_rows32 = (N + 31) / 32;
    const int gb_edges  = (E + TB - 1) / TB;
    const int gb_nodes  = (N + 3) / 4;

    // ---- CSR build (shared by all 3 layers) ----
    zero_ints<<<(2 * N + TB - 1) / TB, TB, 0, stream>>>(deg, 2 * N);
    hist_deg<<<gb_edges, TB, 0, stream>>>(dst, deg);
    scan_offsets<<<1, 1024, 0, stream>>>(deg, offs, N);
    build_csr<<<gb_edges, TB, 0, stream>>>(src, dst, offs, cursor, csr_src);

    // ---- layer 0: 256 -> 8 heads x 16, ELU ----
    gemm_attn<256, 128, 16><<<gb_rows32, 256, 0, stream>>>(x, W0, al0, ar0, feat, elb, erb, N);
    node_flash_agg<8, 16, true><<<gb_nodes, 256, 0, stream>>>(
        offs, csr_src, elb, erb, feat, b0, hbuf, N);

    // ---- layer 1: 128 -> 8 heads x 16, ELU ----
    gemm_attn<128, 128, 16><<<gb_rows32, 256, 0, stream>>>(hbuf, W1, al1, ar1, feat, elb, erb, N);
    node_flash_agg<8, 16, true><<<gb_nodes, 256, 0, stream>>>(
        offs, csr_src, elb, erb, feat, b1, hbuf, N);

    // ---- layer 2: 128 -> 1 head x 64, no act ----
    gemm_attn<128, 64, 64><<<gb_rows32, 256, 0, stream>>>(hbuf, W2, al2, ar2, feat, elb, erb, N);
    node_flash_agg<1, 64, false><<<gb_nodes, 256, 0, stream>>>(
        offs, csr_src, elb, erb, feat, b2, out, N);
}

// Round 12
// 364.426 us; speedup vs baseline: 1.2845x; 1.2845x over previous
//
#include <hip/hip_runtime.h>
#include <hip/hip_bf16.h>
#include <hip/hip_fp16.h>
#include <cstdint>

#define N_NODES 50000
#define N_EDGES 800000

// ---------------------------------------------------------------------------
// feat = X @ W  (stored fp16 for the gather) and el/er fp32 attention dots.
// R10-proven structure: 256 threads, tile 32 rows x DOUT cols; thread (tr,tc)
// owns 2 rows x CN cols; KP=32; ~21 KB LDS; 1563 blocks (~6/CU).
// [R11 lesson: scalar-pipe X (readfirstlane s_load) serializes on lgkmcnt and
//  doubles FETCH -- do not revisit. R8 lesson: reg-staging -> 220 VGPR.]
template<int DIN, int DOUT, int F>
__global__ __launch_bounds__(256) void gemm_attn(
    const float* __restrict__ X, const float* __restrict__ W,
    const float* __restrict__ al, const float* __restrict__ ar,
    __half* __restrict__ feat, float* __restrict__ el, float* __restrict__ er, int N)
{
    constexpr int ROWS = 32;
    constexpr int KP   = 32;
    constexpr int NPH  = DIN / KP;
    constexpr int CN   = DOUT / 16;     // cols per thread (8 or 4)
    constexpr int H    = DOUT / F;
    constexpr int XSTR = KP + 4;        // 36
    constexpr int WSTR = KP * CN + 4;

    __shared__ float xs[ROWS][XSTR];
    __shared__ float ws[16][WSTR];

    const int tid  = threadIdx.x;
    const int tr   = tid >> 4;          // 0..15 row group (2 rows each)
    const int tc   = tid & 15;          // 0..15 col group
    const int row0 = blockIdx.x * ROWS;

    float acc[2][CN];
#pragma unroll
    for (int r = 0; r < 2; ++r)
#pragma unroll
        for (int c = 0; c < CN; ++c) acc[r][c] = 0.f;

    for (int ph = 0; ph < NPH; ++ph) {
        __syncthreads();
        // stage X: 32 rows x KP cols = 256 float4, one per thread
        {
            int r = tid >> 3, q = tid & 7;
            int rr = min(row0 + r, N - 1);
            const float4 v = *reinterpret_cast<const float4*>(
                &X[(size_t)rr * DIN + ph * KP + 4 * q]);
            *reinterpret_cast<float4*>(&xs[r][4 * q]) = v;
        }
        // stage W: KP rows x DOUT cols -> ws[group][k*CN + off]
#pragma unroll
        for (int i = 0; i < KP * (DOUT / 4) / 256; ++i) {
            int s = tid + i * 256;
            int k = s / (DOUT / 4), c4 = (s % (DOUT / 4)) * 4;
            const float4 v = *reinterpret_cast<const float4*>(
                &W[(size_t)(ph * KP + k) * DOUT + c4]);
            *reinterpret_cast<float4*>(&ws[c4 / CN][k * CN + (c4 % CN)]) = v;
        }
        __syncthreads();

#pragma unroll
        for (int k4 = 0; k4 < KP / 4; ++k4) {
            const float4 xv0 = *reinterpret_cast<const float4*>(&xs[tr * 2 + 0][k4 * 4]);
            const float4 xv1 = *reinterpret_cast<const float4*>(&xs[tr * 2 + 1][k4 * 4]);
#pragma unroll
            for (int kk = 0; kk < 4; ++kk) {
                float wv[CN];
#pragma unroll
                for (int j = 0; j < CN / 4; ++j)
                    *reinterpret_cast<float4*>(&wv[4 * j]) =
                        *reinterpret_cast<const float4*>(&ws[tc][(k4 * 4 + kk) * CN + 4 * j]);
                const float x0 = (kk == 0) ? xv0.x : (kk == 1) ? xv0.y
                               : (kk == 2) ? xv0.z : xv0.w;
                const float x1 = (kk == 0) ? xv1.x : (kk == 1) ? xv1.y
                               : (kk == 2) ? xv1.z : xv1.w;
#pragma unroll
                for (int c = 0; c < CN; ++c) {
                    acc[0][c] = fmaf(x0, wv[c], acc[0][c]);
                    acc[1][c] = fmaf(x1, wv[c], acc[1][c]);
                }
            }
        }
    }

    // ---- attention dots: thread-local partial + shfl reduce over F/CN lanes ----
    constexpr int RW = F / CN;          // 2 for L0/L1, 16 for L2
    float alv[CN], arv[CN];
#pragma unroll
    for (int c = 0; c < CN; ++c) { alv[c] = al[tc * CN + c]; arv[c] = ar[tc * CN + c]; }

#pragma unroll
    for (int rr = 0; rr < 2; ++rr) {
        int row = row0 + tr * 2 + rr;
        float pl = 0.f, pr = 0.f;
#pragma unroll
        for (int c = 0; c < CN; ++c) {
            pl = fmaf(acc[rr][c], alv[c], pl);
            pr = fmaf(acc[rr][c], arv[c], pr);
        }
#pragma unroll
        for (int off = 1; off < RW; off <<= 1) {
            pl += __shfl_xor(pl, off);
            pr += __shfl_xor(pr, off);
        }
        if (row < N && (tc % RW) == 0) {
            int h = (tc * CN) / F;
            el[(size_t)row * H + h] = pl;
            er[(size_t)row * H + h] = pr;
        }
    }

    // ---- feat store: fp16, CN cols per thread (8B per float4-group) ----
#pragma unroll
    for (int rr = 0; rr < 2; ++rr) {
        int row = row0 + tr * 2 + rr;
        if (row < N) {
#pragma unroll
            for (int j = 0; j < CN / 4; ++j) {
                __half2 h0 = __floats2half2_rn(acc[rr][4 * j + 0], acc[rr][4 * j + 1]);
                __half2 h1 = __floats2half2_rn(acc[rr][4 * j + 2], acc[rr][4 * j + 3]);
                uint2 pk;
                pk.x = *reinterpret_cast<const unsigned int*>(&h0);
                pk.y = *reinterpret_cast<const unsigned int*>(&h1);
                *reinterpret_cast<uint2*>(&feat[(size_t)row * DOUT + tc * CN + 4 * j]) = pk;
            }
        }
    }
}

// ---------------------------------------------------------------------------
// CSR build (dst-sorted), shared by all 3 layers
__global__ void zero_ints(int* __restrict__ a, int n)
{
    int i = blockIdx.x * blockDim.x + threadIdx.x;
    if (i < n) a[i] = 0;
}

__global__ void hist_deg(const int* __restrict__ dst, int* __restrict__ deg)
{
    int e = blockIdx.x * blockDim.x + threadIdx.x;
    if (e < N_EDGES) atomicAdd(&deg[dst[e]], 1);
}

__global__ __launch_bounds__(1024) void scan_offsets(
    const int* __restrict__ deg, int* __restrict__ offs, int n)
{
    __shared__ int wtot[16], wincl[16];
    __shared__ int carry_s;
    const int tid = threadIdx.x;
    const int lane = tid & 63, wid = tid >> 6;
    if (tid == 0) carry_s = 0;
    __syncthreads();
    for (int base = 0; base < n; base += 1024) {
        int i = base + tid;
        int v = (i < n) ? deg[i] : 0;
        int x = v;
#pragma unroll
        for (int off = 1; off < 64; off <<= 1) {
            int t = __shfl_up(x, off);
            if (lane >= off) x += t;
        }
        if (lane == 63) wtot[wid] = x;
        __syncthreads();
        if (tid < 16) {
            int wx = wtot[tid];
#pragma unroll
            for (int off = 1; off < 16; off <<= 1) {
                int t = __shfl_up(wx, off);
                if (tid >= off) wx += t;
            }
            wincl[tid] = wx;
        }
        __syncthreads();
        int waveExcl = (wid == 0) ? 0 : wincl[wid - 1];
        if (i < n) offs[i] = carry_s + waveExcl + (x - v);
        int total = wincl[15];
        __syncthreads();
        if (tid == 0) carry_s += total;
        __syncthreads();
    }
    if (threadIdx.x == 0) offs[n] = carry_s;
}

__global__ void build_csr(const int* __restrict__ src, const int* __restrict__ dst,
                          const int* __restrict__ offs, int* __restrict__ cursor,
                          int* __restrict__ csr_src)
{
    int e = blockIdx.x * blockDim.x + threadIdx.x;
    if (e >= N_EDGES) return;
    int d = dst[e];
    int p = offs[d] + atomicAdd(&cursor[d], 1);
    csr_src[p] = src[e];
}

// ---------------------------------------------------------------------------
// Fused softmax + aggregation per dst node. One wave per node.
// feat gathered as fp16 (half2 per lane for CPT=2): halves the compulsory
// L2-fill traffic (R10: 209 MB measured ~= traffic floor at fp32).
template<int H, int F, bool ACT>
__global__ __launch_bounds__(256) void node_flash_agg(
    const int* __restrict__ offs, const int* __restrict__ csr_src,
    const float* __restrict__ el, const float* __restrict__ er,
    const __half* __restrict__ feat, const float* __restrict__ bias,
    float* __restrict__ out, int N)
{
    constexpr int D = H * F;
    constexpr int CPT = D / 64;             // 2 or 1
    constexpr int EPC = 64 / H;             // 8 or 64
    constexpr int MAXCH = (H == 8) ? 4 : 1; // fast path: deg<=32 / 64
    constexpr int SB = 8;
    constexpr int NB = MAXCH * EPC / SB;    // feat batches (4 or 8)

    const int wid = threadIdx.x >> 6;
    const int lane = threadIdx.x & 63;
    const int n = blockIdx.x * 4 + wid;
    if (n >= N) return;

    const int beg = offs[n];
    const int deg = offs[n + 1] - beg;

    const int comp0 = CPT * lane;
    const int myhead = comp0 / F;

    if (deg == 0) {
#pragma unroll
        for (int c = 0; c < CPT; ++c) {
            float v = bias[comp0 + c];
            if (ACT) v = (v > 0.f) ? v : expm1f(v);
            out[(size_t)n * D + comp0 + c] = v;
        }
        return;
    }

    const int h = lane % H;
    const int esub = lane / H;
    const float erd = er[(size_t)n * H + h];

    float acc[CPT];
#pragma unroll
    for (int c = 0; c < CPT; ++c) acc[c] = 0.f;

    if (deg <= MAXCH * EPC) {
        // ================= fast path =================
        const int nch = (deg + EPC - 1) / EPC;      // wave-uniform
        int sreg[MAXCH];
        float ex[MAXCH];

#pragma unroll
        for (int j = 0; j < MAXCH; ++j) {
            if (j < nch) {
                sreg[j] = csr_src[beg + min(j * EPC + esub, deg - 1)];
                ex[j] = el[(size_t)sreg[j] * H + h];
            }
        }
        float m = -1e30f;
#pragma unroll
        for (int j = 0; j < MAXCH; ++j) {
            if (j < nch) {
                float v = ex[j] + erd;
                v = (v > 0.f) ? v : 0.2f * v;       // leaky_relu 0.2
                v = (j * EPC + esub < deg) ? v : -1e30f;
                ex[j] = v;
                m = fmaxf(m, v);
            }
        }
#pragma unroll
        for (int off = H; off < 64; off <<= 1)
            m = fmaxf(m, __shfl_xor(m, off));
        float s = 0.f;
#pragma unroll
        for (int j = 0; j < MAXCH; ++j) {
            if (j < nch) { ex[j] = __expf(ex[j] - m); s += ex[j]; }
        }
#pragma unroll
        for (int off = H; off < 64; off <<= 1)
            s += __shfl_xor(s, off);
        const float inv = 1.f / s;
#pragma unroll
        for (int j = 0; j < MAXCH; ++j)
            if (j < nch) ex[j] *= inv;              // normalize upfront

        // ---- weighting: 2-deep ping-pong pipelined fp16 gather ----
        float fvA[SB][CPT], fvB[SB][CPT];
        auto ldb = [&](int j, int g, float (&fv)[SB][CPT]) {
#pragma unroll
            for (int ii = 0; ii < SB; ++ii) {
                int sl = __shfl(sreg[j], (g + ii) * H);
                if constexpr (CPT == 2) {
                    const __half2 t = *reinterpret_cast<const __half2*>(
                        &feat[(size_t)sl * D + comp0]);
                    const float2 f = __half22float2(t);
                    fv[ii][0] = f.x; fv[ii][1] = f.y;
                } else {
                    fv[ii][0] = __half2float(feat[(size_t)sl * D + comp0]);
                }
            }
        };
        auto fmab = [&](int j, int g, float (&fv)[SB][CPT]) {
#pragma unroll
            for (int ii = 0; ii < SB; ++ii) {
                float exb = __shfl(ex[j], (g + ii) * H + myhead);
#pragma unroll
                for (int c = 0; c < CPT; ++c)
                    acc[c] = fmaf(fv[ii][c], exb, acc[c]);
            }
        };

        ldb(0, 0, fvA);                             // prologue
#pragma unroll
        for (int b = 0; b < NB; ++b) {
            if (b * SB < deg) {
                if ((b + 1) * SB < deg) {           // prefetch next batch
                    const int jn = ((b + 1) * SB) / EPC;
                    const int gn = ((b + 1) * SB) % EPC;
                    if ((b & 1) == 0) ldb(jn, gn, fvB);
                    else              ldb(jn, gn, fvA);
                }
                const int j = (b * SB) / EPC;
                const int g = (b * SB) % EPC;
                if ((b & 1) == 0) fmab(j, g, fvA);
                else              fmab(j, g, fvB);
            }
        }
#pragma unroll
        for (int c = 0; c < CPT; ++c) {
            float v = acc[c] + bias[comp0 + c];
            if (ACT) v = (v > 0.f) ? v : expm1f(v);
            acc[c] = v;
        }
    } else {
        // ================= generic online fallback =================
        float m_run = -1e30f, s_run = 0.f;
        int sN = csr_src[beg + min(esub, deg - 1)];
        float elN = el[(size_t)sN * H + h];

        for (int base = 0; base < deg; base += EPC) {
            const int s_mine = sN;
            const float elv = elN;
            const int nb = base + EPC;
            if (nb < deg) {
                sN = csr_src[beg + min(nb + esub, deg - 1)];
                elN = el[(size_t)sN * H + h];
            }
            float v = elv + erd;
            v = (v > 0.f) ? v : 0.2f * v;
            float logit = (base + esub < deg) ? v : -1e30f;

            float cmax = logit;
#pragma unroll
            for (int off = H; off < 64; off <<= 1)
                cmax = fmaxf(cmax, __shfl_xor(cmax, off));
            float nm = fmaxf(m_run, cmax);
            float scale = __expf(m_run - nm);
            float ex = __expf(logit - nm);
            float csum = ex;
#pragma unroll
            for (int off = H; off < 64; off <<= 1)
                csum += __shfl_xor(csum, off);
            s_run = s_run * scale + csum;
            m_run = nm;

            const float sc = __shfl(scale, myhead);
#pragma unroll
            for (int c = 0; c < CPT; ++c) acc[c] *= sc;

            const int active = min(EPC, deg - base);
            for (int g = 0; g < active; g += SB) {
                float fv[SB][CPT];
#pragma unroll
                for (int ii = 0; ii < SB; ++ii) {
                    int sl = __shfl(s_mine, (g + ii) * H);
                    if constexpr (CPT == 2) {
                        const __half2 t = *reinterpret_cast<const __half2*>(
                            &feat[(size_t)sl * D + comp0]);
                        const float2 f = __half22float2(t);
                        fv[ii][0] = f.x; fv[ii][1] = f.y;
                    } else {
                        fv[ii][0] = __half2float(feat[(size_t)sl * D + comp0]);
                    }
                }
#pragma unroll
                for (int ii = 0; ii < SB; ++ii) {
                    float exb = __shfl(ex, (g + ii) * H + myhead);
#pragma unroll
                    for (int c = 0; c < CPT; ++c)
                        acc[c] = fmaf(fv[ii][c], exb, acc[c]);
                }
            }
        }
        const float invb = __shfl(1.f / s_run, myhead);
#pragma unroll
        for (int c = 0; c < CPT; ++c) {
            float v = acc[c] * invb + bias[comp0 + c];
            if (ACT) v = (v > 0.f) ? v : expm1f(v);
            acc[c] = v;
        }
    }

    if constexpr (CPT == 2) {
        *reinterpret_cast<float2*>(&out[(size_t)n * D + comp0]) =
            make_float2(acc[0], acc[1]);
    } else {
        out[(size_t)n * D + comp0] = acc[0];
    }
}

// ---------------------------------------------------------------------------
extern "C" void kernel_launch(void* const* d_in, const int* in_sizes, int n_in,
                              void* d_out, int out_size, void* d_ws, size_t ws_size,
                              hipStream_t stream)
{
    const float* x   = (const float*)d_in[0];
    const int*   src = (const int*)d_in[1];
    const int*   dst = (const int*)d_in[2];
    const float* W0  = (const float*)d_in[3];
    const float* al0 = (const float*)d_in[4];
    const float* ar0 = (const float*)d_in[5];
    const float* b0  = (const float*)d_in[6];
    const float* W1  = (const float*)d_in[7];
    const float* al1 = (const float*)d_in[8];
    const float* ar1 = (const float*)d_in[9];
    const float* b1  = (const float*)d_in[10];
    const float* W2  = (const float*)d_in[11];
    const float* al2 = (const float*)d_in[12];
    const float* ar2 = (const float*)d_in[13];
    const float* b2  = (const float*)d_in[14];
    float* out = (float*)d_out;

    const int N = N_NODES, E = N_EDGES;

    float* ws   = (float*)d_ws;
    __half* feat = (__half*)ws;               // N*128 halves (N*64 float slots)
    float* hbuf = ws + (size_t)N * 128;       // N*128 floats
    float* elb  = hbuf + (size_t)N * 128;     // N*8
    float* erb  = elb + (size_t)N * 8;        // N*8
    int* ibase   = (int*)(erb + (size_t)N * 8);
    int* deg     = ibase;                     // N
    int* cursor  = deg + N;                   // N
    int* offs    = cursor + N;                // N+1
    int* csr_src = offs + N + 1;              // E

    const int TB = 256;
    const int gb_rows32 = (N + 31) / 32;
    const int gb_edges  = (E + TB - 1) / TB;
    const int gb_nodes  = (N + 3) / 4;

    // ---- CSR build (shared by all 3 layers) ----
    zero_ints<<<(2 * N + TB - 1) / TB, TB, 0, stream>>>(deg, 2 * N);
    hist_deg<<<gb_edges, TB, 0, stream>>>(dst, deg);
    scan_offsets<<<1, 1024, 0, stream>>>(deg, offs, N);
    build_csr<<<gb_edges, TB, 0, stream>>>(src, dst, offs, cursor, csr_src);

    // ---- layer 0: 256 -> 8 heads x 16, ELU ----
    gemm_attn<256, 128, 16><<<gb_rows32, 256, 0, stream>>>(x, W0, al0, ar0, feat, elb, erb, N);
    node_flash_agg<8, 16, true><<<gb_nodes, 256, 0, stream>>>(
        offs, csr_src, elb, erb, feat, b0, hbuf, N);

    // ---- layer 1: 128 -> 8 heads x 16, ELU ----
    gemm_attn<128, 128, 16><<<gb_rows32, 256, 0, stream>>>(hbuf, W1, al1, ar1, feat, elb, erb, N);
    node_flash_agg<8, 16, true><<<gb_nodes, 256, 0, stream>>>(
        offs, csr_src, elb, erb, feat, b1, hbuf, N);

    // ---- layer 2: 128 -> 1 head x 64, no act ----
    gemm_attn<128, 64, 64><<<gb_rows32, 256, 0, stream>>>(hbuf, W2, al2, ar2, feat, elb, erb, N);
    node_flash_agg<1, 64, false><<<gb_nodes, 256, 0, stream>>>(
        offs, csr_src, elb, erb, feat, b2, out, N);
}

// Round 13
// 335.627 us; speedup vs baseline: 1.3948x; 1.0858x over previous
//
#include <hip/hip_runtime.h>
#include <hip/hip_bf16.h>
#include <hip/hip_fp16.h>
#include <cstdint>

#define N_NODES 50000
#define N_EDGES 800000

typedef _Float16 half8_t __attribute__((ext_vector_type(8)));
typedef float f32x4 __attribute__((ext_vector_type(4)));

// ---------------------------------------------------------------------------
// Prepack W (fp32 [DIN][DOUT]) into fp16 B-fragment order for 16x16x32 MFMA,
// plus an extra 16-col tile holding Wal/War (el/er as GEMM columns):
//   frag f = (nt*NKS + ks)*64 + lane ; Wp[f*8 + j] =
//     nt <  NT : W[ks*32 + (lane>>4)*8 + j][nt*16 + (lane&15)]
//     nt == NT : n=lane&15: n<H -> dot(W[k][n*F..], al[n]) ; H<=n<2H -> ar ; else 0
template<int DIN, int DOUT, int F>
__global__ void prepack_w(const float* __restrict__ W, const float* __restrict__ al,
                          const float* __restrict__ ar, __half* __restrict__ Wp)
{
    constexpr int NKS = DIN / 32;
    constexpr int NT  = DOUT / 16;
    constexpr int H   = DOUT / F;
    int f = blockIdx.x * blockDim.x + threadIdx.x;
    if (f >= (NT + 1) * NKS * 64) return;
    int lane = f & 63;
    int ks   = (f >> 6) % NKS;
    int nt   = (f >> 6) / NKS;
    int kbase = ks * 32 + (lane >> 4) * 8;
    int n = lane & 15;
    __half h[8];
    if (nt < NT) {
#pragma unroll
        for (int j = 0; j < 8; ++j)
            h[j] = __float2half(W[(size_t)(kbase + j) * DOUT + nt * 16 + n]);
    } else {
#pragma unroll
        for (int j = 0; j < 8; ++j) {
            float s = 0.f;
            if (n < H) {
                for (int ff = 0; ff < F; ++ff)
                    s += W[(size_t)(kbase + j) * DOUT + n * F + ff] * al[n * F + ff];
            } else if (n < 2 * H) {
                int hh = n - H;
                for (int ff = 0; ff < F; ++ff)
                    s += W[(size_t)(kbase + j) * DOUT + hh * F + ff] * ar[hh * F + ff];
            }
            h[j] = __float2half(s);
        }
    }
    *reinterpret_cast<uint4*>(&Wp[(size_t)f * 8]) = *reinterpret_cast<uint4*>(h);
}

// ---------------------------------------------------------------------------
// feat = X @ W via fp16 MFMA (fp32 accum), el/er as extra output columns.
// 256 thr = 4 waves; wave w owns rows row0 + w*16 + (lane&15). Zero LDS,
// zero barriers: A direct from global (fp32 -> fp16 in-reg), B from prepacked
// Wp (coalesced dwordx4, L2-broadcast). C/D: col=lane&15, row=(lane>>4)*4+reg.
template<int DIN, int DOUT, int F>
__global__ __launch_bounds__(256) void gemm_attn_mfma(
    const float* __restrict__ X, const __half* __restrict__ Wp,
    __half* __restrict__ feat, float* __restrict__ el, float* __restrict__ er, int N)
{
    constexpr int NKS = DIN / 32;
    constexpr int NT  = DOUT / 16;
    constexpr int NTT = NT + 1;         // + el/er tile
    constexpr int H   = DOUT / F;

    const int wid  = threadIdx.x >> 6;
    const int lane = threadIdx.x & 63;
    const int row0 = blockIdx.x * 64 + wid * 16;
    const int m    = lane & 15;
    const int kg   = lane >> 4;

    const int rowa = min(row0 + m, N - 1);
    const float* Xr = X + (size_t)rowa * DIN + kg * 8;

    f32x4 acc[NTT];
#pragma unroll
    for (int i = 0; i < NTT; ++i) acc[i] = (f32x4){0.f, 0.f, 0.f, 0.f};

#pragma unroll
    for (int ks = 0; ks < NKS; ++ks) {
        const float4 xa = *reinterpret_cast<const float4*>(Xr + ks * 32);
        const float4 xb = *reinterpret_cast<const float4*>(Xr + ks * 32 + 4);
        half8_t a;
        a[0] = (_Float16)xa.x; a[1] = (_Float16)xa.y;
        a[2] = (_Float16)xa.z; a[3] = (_Float16)xa.w;
        a[4] = (_Float16)xb.x; a[5] = (_Float16)xb.y;
        a[6] = (_Float16)xb.z; a[7] = (_Float16)xb.w;
#pragma unroll
        for (int nt = 0; nt < NTT; ++nt) {
            const half8_t b = *reinterpret_cast<const half8_t*>(
                Wp + ((size_t)(nt * NKS + ks) * 64 + lane) * 8);
            acc[nt] = __builtin_amdgcn_mfma_f32_16x16x32_f16(a, b, acc[nt], 0, 0, 0);
        }
    }

    // ---- store: C/D layout col=lane&15, row=(lane>>4)*4+reg ----
    const int q = lane >> 4;
#pragma unroll
    for (int reg = 0; reg < 4; ++reg) {
        const int row = row0 + 4 * q + reg;
        if (row < N) {
#pragma unroll
            for (int nt = 0; nt < NT; ++nt)
                feat[(size_t)row * DOUT + nt * 16 + m] = __float2half(acc[nt][reg]);
            const float v = acc[NT][reg];
            if (m < H)          el[(size_t)row * H + m] = v;
            else if (m < 2 * H) er[(size_t)row * H + (m - H)] = v;
        }
    }
}

// ---------------------------------------------------------------------------
// CSR build (dst-sorted), shared by all 3 layers
__global__ void zero_ints(int* __restrict__ a, int n)
{
    int i = blockIdx.x * blockDim.x + threadIdx.x;
    if (i < n) a[i] = 0;
}

__global__ void hist_deg(const int* __restrict__ dst, int* __restrict__ deg)
{
    int e = blockIdx.x * blockDim.x + threadIdx.x;
    if (e < N_EDGES) atomicAdd(&deg[dst[e]], 1);
}

__global__ __launch_bounds__(1024) void scan_offsets(
    const int* __restrict__ deg, int* __restrict__ offs, int n)
{
    __shared__ int wtot[16], wincl[16];
    __shared__ int carry_s;
    const int tid = threadIdx.x;
    const int lane = tid & 63, wid = tid >> 6;
    if (tid == 0) carry_s = 0;
    __syncthreads();
    for (int base = 0; base < n; base += 1024) {
        int i = base + tid;
        int v = (i < n) ? deg[i] : 0;
        int x = v;
#pragma unroll
        for (int off = 1; off < 64; off <<= 1) {
            int t = __shfl_up(x, off);
            if (lane >= off) x += t;
        }
        if (lane == 63) wtot[wid] = x;
        __syncthreads();
        if (tid < 16) {
            int wx = wtot[tid];
#pragma unroll
            for (int off = 1; off < 16; off <<= 1) {
                int t = __shfl_up(wx, off);
                if (tid >= off) wx += t;
            }
            wincl[tid] = wx;
        }
        __syncthreads();
        int waveExcl = (wid == 0) ? 0 : wincl[wid - 1];
        if (i < n) offs[i] = carry_s + waveExcl + (x - v);
        int total = wincl[15];
        __syncthreads();
        if (tid == 0) carry_s += total;
        __syncthreads();
    }
    if (threadIdx.x == 0) offs[n] = carry_s;
}

__global__ void build_csr(const int* __restrict__ src, const int* __restrict__ dst,
                          const int* __restrict__ offs, int* __restrict__ cursor,
                          int* __restrict__ csr_src)
{
    int e = blockIdx.x * blockDim.x + threadIdx.x;
    if (e >= N_EDGES) return;
    int d = dst[e];
    int p = offs[d] + atomicAdd(&cursor[d], 1);
    csr_src[p] = src[e];
}

// ---------------------------------------------------------------------------
// Fused softmax + aggregation per dst node. One wave per node. fp16 feat
// gather (R12-proven: halves the compulsory L2-fill traffic).
template<int H, int F, bool ACT>
__global__ __launch_bounds__(256) void node_flash_agg(
    const int* __restrict__ offs, const int* __restrict__ csr_src,
    const float* __restrict__ el, const float* __restrict__ er,
    const __half* __restrict__ feat, const float* __restrict__ bias,
    float* __restrict__ out, int N)
{
    constexpr int D = H * F;
    constexpr int CPT = D / 64;             // 2 or 1
    constexpr int EPC = 64 / H;             // 8 or 64
    constexpr int MAXCH = (H == 8) ? 4 : 1; // fast path: deg<=32 / 64
    constexpr int SB = 8;
    constexpr int NB = MAXCH * EPC / SB;    // feat batches (4 or 8)

    const int wid = threadIdx.x >> 6;
    const int lane = threadIdx.x & 63;
    const int n = blockIdx.x * 4 + wid;
    if (n >= N) return;

    const int beg = offs[n];
    const int deg = offs[n + 1] - beg;

    const int comp0 = CPT * lane;
    const int myhead = comp0 / F;

    if (deg == 0) {
#pragma unroll
        for (int c = 0; c < CPT; ++c) {
            float v = bias[comp0 + c];
            if (ACT) v = (v > 0.f) ? v : expm1f(v);
            out[(size_t)n * D + comp0 + c] = v;
        }
        return;
    }

    const int h = lane % H;
    const int esub = lane / H;
    const float erd = er[(size_t)n * H + h];

    float acc[CPT];
#pragma unroll
    for (int c = 0; c < CPT; ++c) acc[c] = 0.f;

    if (deg <= MAXCH * EPC) {
        // ================= fast path =================
        const int nch = (deg + EPC - 1) / EPC;      // wave-uniform
        int sreg[MAXCH];
        float ex[MAXCH];

#pragma unroll
        for (int j = 0; j < MAXCH; ++j) {
            if (j < nch) {
                sreg[j] = csr_src[beg + min(j * EPC + esub, deg - 1)];
                ex[j] = el[(size_t)sreg[j] * H + h];
            }
        }
        float m = -1e30f;
#pragma unroll
        for (int j = 0; j < MAXCH; ++j) {
            if (j < nch) {
                float v = ex[j] + erd;
                v = (v > 0.f) ? v : 0.2f * v;       // leaky_relu 0.2
                v = (j * EPC + esub < deg) ? v : -1e30f;
                ex[j] = v;
                m = fmaxf(m, v);
            }
        }
#pragma unroll
        for (int off = H; off < 64; off <<= 1)
            m = fmaxf(m, __shfl_xor(m, off));
        float s = 0.f;
#pragma unroll
        for (int j = 0; j < MAXCH; ++j) {
            if (j < nch) { ex[j] = __expf(ex[j] - m); s += ex[j]; }
        }
#pragma unroll
        for (int off = H; off < 64; off <<= 1)
            s += __shfl_xor(s, off);
        const float inv = 1.f / s;
#pragma unroll
        for (int j = 0; j < MAXCH; ++j)
            if (j < nch) ex[j] *= inv;              // normalize upfront

        // ---- weighting: 2-deep ping-pong pipelined fp16 gather ----
        float fvA[SB][CPT], fvB[SB][CPT];
        auto ldb = [&](int j, int g, float (&fv)[SB][CPT]) {
#pragma unroll
            for (int ii = 0; ii < SB; ++ii) {
                int sl = __shfl(sreg[j], (g + ii) * H);
                if constexpr (CPT == 2) {
                    const __half2 t = *reinterpret_cast<const __half2*>(
                        &feat[(size_t)sl * D + comp0]);
                    const float2 f = __half22float2(t);
                    fv[ii][0] = f.x; fv[ii][1] = f.y;
                } else {
                    fv[ii][0] = __half2float(feat[(size_t)sl * D + comp0]);
                }
            }
        };
        auto fmab = [&](int j, int g, float (&fv)[SB][CPT]) {
#pragma unroll
            for (int ii = 0; ii < SB; ++ii) {
                float exb = __shfl(ex[j], (g + ii) * H + myhead);
#pragma unroll
                for (int c = 0; c < CPT; ++c)
                    acc[c] = fmaf(fv[ii][c], exb, acc[c]);
            }
        };

        ldb(0, 0, fvA);                             // prologue
#pragma unroll
        for (int b = 0; b < NB; ++b) {
            if (b * SB < deg) {
                if ((b + 1) * SB < deg) {           // prefetch next batch
                    const int jn = ((b + 1) * SB) / EPC;
                    const int gn = ((b + 1) * SB) % EPC;
                    if ((b & 1) == 0) ldb(jn, gn, fvB);
                    else              ldb(jn, gn, fvA);
                }
                const int j = (b * SB) / EPC;
                const int g = (b * SB) % EPC;
                if ((b & 1) == 0) fmab(j, g, fvA);
                else              fmab(j, g, fvB);
            }
        }
#pragma unroll
        for (int c = 0; c < CPT; ++c) {
            float v = acc[c] + bias[comp0 + c];
            if (ACT) v = (v > 0.f) ? v : expm1f(v);
            acc[c] = v;
        }
    } else {
        // ================= generic online fallback =================
        float m_run = -1e30f, s_run = 0.f;
        int sN = csr_src[beg + min(esub, deg - 1)];
        float elN = el[(size_t)sN * H + h];

        for (int base = 0; base < deg; base += EPC) {
            const int s_mine = sN;
            const float elv = elN;
            const int nb = base + EPC;
            if (nb < deg) {
                sN = csr_src[beg + min(nb + esub, deg - 1)];
                elN = el[(size_t)sN * H + h];
            }
            float v = elv + erd;
            v = (v > 0.f) ? v : 0.2f * v;
            float logit = (base + esub < deg) ? v : -1e30f;

            float cmax = logit;
#pragma unroll
            for (int off = H; off < 64; off <<= 1)
                cmax = fmaxf(cmax, __shfl_xor(cmax, off));
            float nm = fmaxf(m_run, cmax);
            float scale = __expf(m_run - nm);
            float ex = __expf(logit - nm);
            float csum = ex;
#pragma unroll
            for (int off = H; off < 64; off <<= 1)
                csum += __shfl_xor(csum, off);
            s_run = s_run * scale + csum;
            m_run = nm;

            const float sc = __shfl(scale, myhead);
#pragma unroll
            for (int c = 0; c < CPT; ++c) acc[c] *= sc;

            const int active = min(EPC, deg - base);
            for (int g = 0; g < active; g += SB) {
                float fv[SB][CPT];
#pragma unroll
                for (int ii = 0; ii < SB; ++ii) {
                    int sl = __shfl(s_mine, (g + ii) * H);
                    if constexpr (CPT == 2) {
                        const __half2 t = *reinterpret_cast<const __half2*>(
                            &feat[(size_t)sl * D + comp0]);
                        const float2 f = __half22float2(t);
                        fv[ii][0] = f.x; fv[ii][1] = f.y;
                    } else {
                        fv[ii][0] = __half2float(feat[(size_t)sl * D + comp0]);
                    }
                }
#pragma unroll
                for (int ii = 0; ii < SB; ++ii) {
                    float exb = __shfl(ex, (g + ii) * H + myhead);
#pragma unroll
                    for (int c = 0; c < CPT; ++c)
                        acc[c] = fmaf(fv[ii][c], exb, acc[c]);
                }
            }
        }
        const float invb = __shfl(1.f / s_run, myhead);
#pragma unroll
        for (int c = 0; c < CPT; ++c) {
            float v = acc[c] * invb + bias[comp0 + c];
            if (ACT) v = (v > 0.f) ? v : expm1f(v);
            acc[c] = v;
        }
    }

    if constexpr (CPT == 2) {
        *reinterpret_cast<float2*>(&out[(size_t)n * D + comp0]) =
            make_float2(acc[0], acc[1]);
    } else {
        out[(size_t)n * D + comp0] = acc[0];
    }
}

// ---------------------------------------------------------------------------
extern "C" void kernel_launch(void* const* d_in, const int* in_sizes, int n_in,
                              void* d_out, int out_size, void* d_ws, size_t ws_size,
                              hipStream_t stream)
{
    const float* x   = (const float*)d_in[0];
    const int*   src = (const int*)d_in[1];
    const int*   dst = (const int*)d_in[2];
    const float* W0  = (const float*)d_in[3];
    const float* al0 = (const float*)d_in[4];
    const float* ar0 = (const float*)d_in[5];
    const float* b0  = (const float*)d_in[6];
    const float* W1  = (const float*)d_in[7];
    const float* al1 = (const float*)d_in[8];
    const float* ar1 = (const float*)d_in[9];
    const float* b1  = (const float*)d_in[10];
    const float* W2  = (const float*)d_in[11];
    const float* al2 = (const float*)d_in[12];
    const float* ar2 = (const float*)d_in[13];
    const float* b2  = (const float*)d_in[14];
    float* out = (float*)d_out;

    const int N = N_NODES, E = N_EDGES;

    // Wp frag counts: (NT+1)*NKS*64 frags * 8 halves
    const size_t wp0_h = 9 * 8 * 64 * 8;   // 36864 halves
    const size_t wp1_h = 9 * 4 * 64 * 8;   // 18432
    const size_t wp2_h = 5 * 4 * 64 * 8;   // 10240

    __half* Wp0 = (__half*)d_ws;           // 16B-aligned (ws base)
    __half* Wp1 = Wp0 + wp0_h;
    __half* Wp2 = Wp1 + wp1_h;
    float* fbase = (float*)(Wp2 + wp2_h + 2048);  // pad, stays 16B-aligned

    __half* feat = (__half*)fbase;            // N*128 halves = N*64 float slots
    float* hbuf = fbase + (size_t)N * 64;     // N*128 floats
    float* elb  = hbuf + (size_t)N * 128;     // N*8
    float* erb  = elb + (size_t)N * 8;        // N*8
    int* ibase   = (int*)(erb + (size_t)N * 8);
    int* deg     = ibase;                     // N
    int* cursor  = deg + N;                   // N
    int* offs    = cursor + N;                // N+1
    int* csr_src = offs + N + 1;              // E

    const int TB = 256;
    const int gb_rows64 = (N + 63) / 64;      // 782
    const int gb_edges  = (E + TB - 1) / TB;
    const int gb_nodes  = (N + 3) / 4;

    // ---- prepack W fragments (independent of graph data) ----
    prepack_w<256, 128, 16><<<(9 * 8 * 64 + TB - 1) / TB, TB, 0, stream>>>(W0, al0, ar0, Wp0);
    prepack_w<128, 128, 16><<<(9 * 4 * 64 + TB - 1) / TB, TB, 0, stream>>>(W1, al1, ar1, Wp1);
    prepack_w<128, 64, 64><<<(5 * 4 * 64 + TB - 1) / TB, TB, 0, stream>>>(W2, al2, ar2, Wp2);

    // ---- CSR build (shared by all 3 layers) ----
    zero_ints<<<(2 * N + TB - 1) / TB, TB, 0, stream>>>(deg, 2 * N);
    hist_deg<<<gb_edges, TB, 0, stream>>>(dst, deg);
    scan_offsets<<<1, 1024, 0, stream>>>(deg, offs, N);
    build_csr<<<gb_edges, TB, 0, stream>>>(src, dst, offs, cursor, csr_src);

    // ---- layer 0: 256 -> 8 heads x 16, ELU ----
    gemm_attn_mfma<256, 128, 16><<<gb_rows64, 256, 0, stream>>>(x, Wp0, feat, elb, erb, N);
    node_flash_agg<8, 16, true><<<gb_nodes, 256, 0, stream>>>(
        offs, csr_src, elb, erb, feat, b0, hbuf, N);

    // ---- layer 1: 128 -> 8 heads x 16, ELU ----
    gemm_attn_mfma<128, 128, 16><<<gb_rows64, 256, 0, stream>>>(hbuf, Wp1, feat, elb, erb, N);
    node_flash_agg<8, 16, true><<<gb_nodes, 256, 0, stream>>>(
        offs, csr_src, elb, erb, feat, b1, hbuf, N);

    // ---- layer 2: 128 -> 1 head x 64, no act ----
    gemm_attn_mfma<128, 64, 64><<<gb_rows64, 256, 0, stream>>>(hbuf, Wp2, feat, elb, erb, N);
    node_flash_agg<1, 64, false><<<gb_nodes, 256, 0, stream>>>(
        offs, csr_src, elb, erb, feat, b2, out, N);
}

// Round 14
// 297.072 us; speedup vs baseline: 1.5758x; 1.1298x over previous
//
#include <hip/hip_runtime.h>
#include <hip/hip_bf16.h>
#include <hip/hip_fp16.h>
#include <cstdint>

#define N_NODES 50000
#define N_EDGES 800000

typedef _Float16 half8_t __attribute__((ext_vector_type(8)));
typedef float f32x4 __attribute__((ext_vector_type(4)));

// ---------------------------------------------------------------------------
// Prepack W (fp32 [DIN][DOUT]) into fp16 B-fragment order for 16x16x32 MFMA,
// plus an extra 16-col tile holding Wal/War (el/er as GEMM columns).
template<int DIN, int DOUT, int F>
__global__ void prepack_w(const float* __restrict__ W, const float* __restrict__ al,
                          const float* __restrict__ ar, __half* __restrict__ Wp)
{
    constexpr int NKS = DIN / 32;
    constexpr int NT  = DOUT / 16;
    constexpr int H   = DOUT / F;
    int f = blockIdx.x * blockDim.x + threadIdx.x;
    if (f >= (NT + 1) * NKS * 64) return;
    int lane = f & 63;
    int ks   = (f >> 6) % NKS;
    int nt   = (f >> 6) / NKS;
    int kbase = ks * 32 + (lane >> 4) * 8;
    int n = lane & 15;
    __half h[8];
    if (nt < NT) {
#pragma unroll
        for (int j = 0; j < 8; ++j)
            h[j] = __float2half(W[(size_t)(kbase + j) * DOUT + nt * 16 + n]);
    } else {
#pragma unroll
        for (int j = 0; j < 8; ++j) {
            float s = 0.f;
            if (n < H) {
                for (int ff = 0; ff < F; ++ff)
                    s += W[(size_t)(kbase + j) * DOUT + n * F + ff] * al[n * F + ff];
            } else if (n < 2 * H) {
                int hh = n - H;
                for (int ff = 0; ff < F; ++ff)
                    s += W[(size_t)(kbase + j) * DOUT + hh * F + ff] * ar[hh * F + ff];
            }
            h[j] = __float2half(s);
        }
    }
    *reinterpret_cast<uint4*>(&Wp[(size_t)f * 8]) = *reinterpret_cast<uint4*>(h);
}

// ---------------------------------------------------------------------------
// feat = X @ W via fp16 MFMA (fp32 accum), el/er as extra output columns.
// Zero LDS / zero barriers. X (scattered 16-segment gather) software-pipelined
// one k-step ahead so its latency hides under the MFMAs of the current step.
template<int DIN, int DOUT, int F>
__global__ __launch_bounds__(256) void gemm_attn_mfma(
    const float* __restrict__ X, const __half* __restrict__ Wp,
    __half* __restrict__ feat, float* __restrict__ el, float* __restrict__ er, int N)
{
    constexpr int NKS = DIN / 32;
    constexpr int NT  = DOUT / 16;
    constexpr int NTT = NT + 1;         // + el/er tile
    constexpr int H   = DOUT / F;

    const int wid  = threadIdx.x >> 6;
    const int lane = threadIdx.x & 63;
    const int row0 = blockIdx.x * 64 + wid * 16;
    const int m    = lane & 15;
    const int kg   = lane >> 4;

    const int rowa = min(row0 + m, N - 1);
    const float* Xr = X + (size_t)rowa * DIN + kg * 8;

    f32x4 acc[NTT];
#pragma unroll
    for (int i = 0; i < NTT; ++i) acc[i] = (f32x4){0.f, 0.f, 0.f, 0.f};

    float4 xa = *reinterpret_cast<const float4*>(Xr);
    float4 xb = *reinterpret_cast<const float4*>(Xr + 4);

#pragma unroll
    for (int ks = 0; ks < NKS; ++ks) {
        float4 xan = xa, xbn = xb;
        if (ks + 1 < NKS) {             // prefetch next k-step's X
            xan = *reinterpret_cast<const float4*>(Xr + (ks + 1) * 32);
            xbn = *reinterpret_cast<const float4*>(Xr + (ks + 1) * 32 + 4);
        }
        half8_t a;
        a[0] = (_Float16)xa.x; a[1] = (_Float16)xa.y;
        a[2] = (_Float16)xa.z; a[3] = (_Float16)xa.w;
        a[4] = (_Float16)xb.x; a[5] = (_Float16)xb.y;
        a[6] = (_Float16)xb.z; a[7] = (_Float16)xb.w;
#pragma unroll
        for (int nt = 0; nt < NTT; ++nt) {
            const half8_t b = *reinterpret_cast<const half8_t*>(
                Wp + ((size_t)(nt * NKS + ks) * 64 + lane) * 8);
            acc[nt] = __builtin_amdgcn_mfma_f32_16x16x32_f16(a, b, acc[nt], 0, 0, 0);
        }
        xa = xan; xb = xbn;
    }

    // ---- store: C/D layout col=lane&15, row=(lane>>4)*4+reg ----
    const int q = lane >> 4;
#pragma unroll
    for (int reg = 0; reg < 4; ++reg) {
        const int row = row0 + 4 * q + reg;
        if (row < N) {
#pragma unroll
            for (int nt = 0; nt < NT; ++nt)
                feat[(size_t)row * DOUT + nt * 16 + m] = __float2half(acc[nt][reg]);
            const float v = acc[NT][reg];
            if (m < H)          el[(size_t)row * H + m] = v;
            else if (m < 2 * H) er[(size_t)row * H + (m - H)] = v;
        }
    }
}

// ---------------------------------------------------------------------------
// CSR build (dst-sorted), shared by all 3 layers
__global__ void zero_ints(int* __restrict__ a, int n)
{
    int i = blockIdx.x * blockDim.x + threadIdx.x;
    if (i < n) a[i] = 0;
}

__global__ void hist_deg(const int* __restrict__ dst, int* __restrict__ deg)
{
    int e = blockIdx.x * blockDim.x + threadIdx.x;
    if (e < N_EDGES) atomicAdd(&deg[dst[e]], 1);
}

// Multi-block scan, 3 stages (replaces the serial single-block scan).
__global__ __launch_bounds__(1024) void scan_partials(
    const int* __restrict__ deg, int* __restrict__ btot, int n)
{
    __shared__ int wsum[16];
    const int tid = threadIdx.x;
    const int lane = tid & 63, wid = tid >> 6;
    int i = blockIdx.x * 1024 + tid;
    int v = (i < n) ? deg[i] : 0;
#pragma unroll
    for (int off = 1; off < 64; off <<= 1) v += __shfl_xor(v, off);
    if (lane == 0) wsum[wid] = v;
    __syncthreads();
    if (tid < 16) {
        int w = wsum[tid];
#pragma unroll
        for (int off = 1; off < 16; off <<= 1) w += __shfl_xor(w, off, 16);
        if (tid == 0) btot[blockIdx.x] = w;
    }
}

__global__ void scan_btot(int* __restrict__ btot, int nb)
{
    int tid = threadIdx.x;          // one wave, nb <= 64
    int v = (tid < nb) ? btot[tid] : 0;
    int x = v;
#pragma unroll
    for (int off = 1; off < 64; off <<= 1) {
        int t = __shfl_up(x, off);
        if (tid >= off) x += t;
    }
    if (tid < nb) btot[tid] = x - v;    // exclusive
}

__global__ __launch_bounds__(1024) void scan_final(
    const int* __restrict__ deg, const int* __restrict__ bcar,
    int* __restrict__ offs, int n)
{
    __shared__ int wtot[16], wincl[16];
    const int tid = threadIdx.x;
    const int lane = tid & 63, wid = tid >> 6;
    int i = blockIdx.x * 1024 + tid;
    int v = (i < n) ? deg[i] : 0;
    int x = v;
#pragma unroll
    for (int off = 1; off < 64; off <<= 1) {
        int t = __shfl_up(x, off);
        if (lane >= off) x += t;
    }
    if (lane == 63) wtot[wid] = x;
    __syncthreads();
    if (tid < 16) {
        int wx = wtot[tid];
#pragma unroll
        for (int off = 1; off < 16; off <<= 1) {
            int t = __shfl_up(wx, off, 16);
            if (tid >= off) wx += t;
        }
        wincl[tid] = wx;
    }
    __syncthreads();
    int waveExcl = (wid == 0) ? 0 : wincl[wid - 1];
    if (i < n) offs[i] = bcar[blockIdx.x] + waveExcl + (x - v);
    if (i == 0) offs[n] = N_EDGES;
}

__global__ void build_csr(const int* __restrict__ src, const int* __restrict__ dst,
                          const int* __restrict__ offs, int* __restrict__ cursor,
                          int* __restrict__ csr_src)
{
    int e = blockIdx.x * blockDim.x + threadIdx.x;
    if (e >= N_EDGES) return;
    int d = dst[e];
    int p = offs[d] + atomicAdd(&cursor[d], 1);
    csr_src[p] = src[e];
}

// ---------------------------------------------------------------------------
// Fused softmax + aggregation per dst node. One wave per node. fp16 feat
// gather; ELU via __expf (absolute tol 1e-2 -> expm1 precision unneeded).
template<int H, int F, bool ACT>
__global__ __launch_bounds__(256) void node_flash_agg(
    const int* __restrict__ offs, const int* __restrict__ csr_src,
    const float* __restrict__ el, const float* __restrict__ er,
    const __half* __restrict__ feat, const float* __restrict__ bias,
    float* __restrict__ out, int N)
{
    constexpr int D = H * F;
    constexpr int CPT = D / 64;             // 2 or 1
    constexpr int EPC = 64 / H;             // 8 or 64
    constexpr int MAXCH = (H == 8) ? 4 : 1; // fast path: deg<=32 / 64
    constexpr int SB = 8;
    constexpr int NB = MAXCH * EPC / SB;    // feat batches (4 or 8)

    const int wid = threadIdx.x >> 6;
    const int lane = threadIdx.x & 63;
    const int n = blockIdx.x * 4 + wid;
    if (n >= N) return;

    const int beg = offs[n];
    const int deg = offs[n + 1] - beg;

    const int comp0 = CPT * lane;
    const int myhead = comp0 / F;

    if (deg == 0) {
#pragma unroll
        for (int c = 0; c < CPT; ++c) {
            float v = bias[comp0 + c];
            if (ACT) v = (v > 0.f) ? v : (__expf(v) - 1.f);
            out[(size_t)n * D + comp0 + c] = v;
        }
        return;
    }

    const int h = lane % H;
    const int esub = lane / H;
    const float erd = er[(size_t)n * H + h];

    float acc[CPT];
#pragma unroll
    for (int c = 0; c < CPT; ++c) acc[c] = 0.f;

    if (deg <= MAXCH * EPC) {
        // ================= fast path =================
        const int nch = (deg + EPC - 1) / EPC;      // wave-uniform
        int sreg[MAXCH];
        float ex[MAXCH];

#pragma unroll
        for (int j = 0; j < MAXCH; ++j) {
            if (j < nch) {
                sreg[j] = csr_src[beg + min(j * EPC + esub, deg - 1)];
                ex[j] = el[(size_t)sreg[j] * H + h];
            }
        }
        float m = -1e30f;
#pragma unroll
        for (int j = 0; j < MAXCH; ++j) {
            if (j < nch) {
                float v = ex[j] + erd;
                v = (v > 0.f) ? v : 0.2f * v;       // leaky_relu 0.2
                v = (j * EPC + esub < deg) ? v : -1e30f;
                ex[j] = v;
                m = fmaxf(m, v);
            }
        }
#pragma unroll
        for (int off = H; off < 64; off <<= 1)
            m = fmaxf(m, __shfl_xor(m, off));
        float s = 0.f;
#pragma unroll
        for (int j = 0; j < MAXCH; ++j) {
            if (j < nch) { ex[j] = __expf(ex[j] - m); s += ex[j]; }
        }
#pragma unroll
        for (int off = H; off < 64; off <<= 1)
            s += __shfl_xor(s, off);
        const float inv = 1.f / s;
#pragma unroll
        for (int j = 0; j < MAXCH; ++j)
            if (j < nch) ex[j] *= inv;              // normalize upfront

        // ---- weighting: 2-deep ping-pong pipelined fp16 gather ----
        float fvA[SB][CPT], fvB[SB][CPT];
        auto ldb = [&](int j, int g, float (&fv)[SB][CPT]) {
#pragma unroll
            for (int ii = 0; ii < SB; ++ii) {
                int sl = __shfl(sreg[j], (g + ii) * H);
                if constexpr (CPT == 2) {
                    const __half2 t = *reinterpret_cast<const __half2*>(
                        &feat[(size_t)sl * D + comp0]);
                    const float2 f = __half22float2(t);
                    fv[ii][0] = f.x; fv[ii][1] = f.y;
                } else {
                    fv[ii][0] = __half2float(feat[(size_t)sl * D + comp0]);
                }
            }
        };
        auto fmab = [&](int j, int g, float (&fv)[SB][CPT]) {
#pragma unroll
            for (int ii = 0; ii < SB; ++ii) {
                float exb = __shfl(ex[j], (g + ii) * H + myhead);
#pragma unroll
                for (int c = 0; c < CPT; ++c)
                    acc[c] = fmaf(fv[ii][c], exb, acc[c]);
            }
        };

        ldb(0, 0, fvA);                             // prologue
#pragma unroll
        for (int b = 0; b < NB; ++b) {
            if (b * SB < deg) {
                if ((b + 1) * SB < deg) {           // prefetch next batch
                    const int jn = ((b + 1) * SB) / EPC;
                    const int gn = ((b + 1) * SB) % EPC;
                    if ((b & 1) == 0) ldb(jn, gn, fvB);
                    else              ldb(jn, gn, fvA);
                }
                const int j = (b * SB) / EPC;
                const int g = (b * SB) % EPC;
                if ((b & 1) == 0) fmab(j, g, fvA);
                else              fmab(j, g, fvB);
            }
        }
#pragma unroll
        for (int c = 0; c < CPT; ++c) {
            float v = acc[c] + bias[comp0 + c];
            if (ACT) v = (v > 0.f) ? v : (__expf(v) - 1.f);
            acc[c] = v;
        }
    } else {
        // ================= generic online fallback =================
        float m_run = -1e30f, s_run = 0.f;
        int sN = csr_src[beg + min(esub, deg - 1)];
        float elN = el[(size_t)sN * H + h];

        for (int base = 0; base < deg; base += EPC) {
            const int s_mine = sN;
            const float elv = elN;
            const int nb = base + EPC;
            if (nb < deg) {
                sN = csr_src[beg + min(nb + esub, deg - 1)];
                elN = el[(size_t)sN * H + h];
            }
            float v = elv + erd;
            v = (v > 0.f) ? v : 0.2f * v;
            float logit = (base + esub < deg) ? v : -1e30f;

            float cmax = logit;
#pragma unroll
            for (int off = H; off < 64; off <<= 1)
                cmax = fmaxf(cmax, __shfl_xor(cmax, off));
            float nm = fmaxf(m_run, cmax);
            float scale = __expf(m_run - nm);
            float ex = __expf(logit - nm);
            float csum = ex;
#pragma unroll
            for (int off = H; off < 64; off <<= 1)
                csum += __shfl_xor(csum, off);
            s_run = s_run * scale + csum;
            m_run = nm;

            const float sc = __shfl(scale, myhead);
#pragma unroll
            for (int c = 0; c < CPT; ++c) acc[c] *= sc;

            const int active = min(EPC, deg - base);
            for (int g = 0; g < active; g += SB) {
                float fv[SB][CPT];
#pragma unroll
                for (int ii = 0; ii < SB; ++ii) {
                    int sl = __shfl(s_mine, (g + ii) * H);
                    if constexpr (CPT == 2) {
                        const __half2 t = *reinterpret_cast<const __half2*>(
                            &feat[(size_t)sl * D + comp0]);
                        const float2 f = __half22float2(t);
                        fv[ii][0] = f.x; fv[ii][1] = f.y;
                    } else {
                        fv[ii][0] = __half2float(feat[(size_t)sl * D + comp0]);
                    }
                }
#pragma unroll
                for (int ii = 0; ii < SB; ++ii) {
                    float exb = __shfl(ex, (g + ii) * H + myhead);
#pragma unroll
                    for (int c = 0; c < CPT; ++c)
                        acc[c] = fmaf(fv[ii][c], exb, acc[c]);
                }
            }
        }
        const float invb = __shfl(1.f / s_run, myhead);
#pragma unroll
        for (int c = 0; c < CPT; ++c) {
            float v = acc[c] * invb + bias[comp0 + c];
            if (ACT) v = (v > 0.f) ? v : (__expf(v) - 1.f);
            acc[c] = v;
        }
    }

    if constexpr (CPT == 2) {
        *reinterpret_cast<float2*>(&out[(size_t)n * D + comp0]) =
            make_float2(acc[0], acc[1]);
    } else {
        out[(size_t)n * D + comp0] = acc[0];
    }
}

// ---------------------------------------------------------------------------
extern "C" void kernel_launch(void* const* d_in, const int* in_sizes, int n_in,
                              void* d_out, int out_size, void* d_ws, size_t ws_size,
                              hipStream_t stream)
{
    const float* x   = (const float*)d_in[0];
    const int*   src = (const int*)d_in[1];
    const int*   dst = (const int*)d_in[2];
    const float* W0  = (const float*)d_in[3];
    const float* al0 = (const float*)d_in[4];
    const float* ar0 = (const float*)d_in[5];
    const float* b0  = (const float*)d_in[6];
    const float* W1  = (const float*)d_in[7];
    const float* al1 = (const float*)d_in[8];
    const float* ar1 = (const float*)d_in[9];
    const float* b1  = (const float*)d_in[10];
    const float* W2  = (const float*)d_in[11];
    const float* al2 = (const float*)d_in[12];
    const float* ar2 = (const float*)d_in[13];
    const float* b2  = (const float*)d_in[14];
    float* out = (float*)d_out;

    const int N = N_NODES, E = N_EDGES;

    // Wp frag counts: (NT+1)*NKS*64 frags * 8 halves
    const size_t wp0_h = 9 * 8 * 64 * 8;
    const size_t wp1_h = 9 * 4 * 64 * 8;
    const size_t wp2_h = 5 * 4 * 64 * 8;

    __half* Wp0 = (__half*)d_ws;
    __half* Wp1 = Wp0 + wp0_h;
    __half* Wp2 = Wp1 + wp1_h;
    float* fbase = (float*)(Wp2 + wp2_h + 2048);

    __half* feat = (__half*)fbase;            // N*128 halves
    float* hbuf = fbase + (size_t)N * 64;     // N*128 floats
    float* elb  = hbuf + (size_t)N * 128;     // N*8
    float* erb  = elb + (size_t)N * 8;        // N*8
    int* ibase   = (int*)(erb + (size_t)N * 8);
    int* deg     = ibase;                     // N
    int* cursor  = deg + N;                   // N
    int* offs    = cursor + N;                // N+1
    int* csr_src = offs + N + 1;              // E
    int* btot    = csr_src + E;               // 64 block partials

    const int TB = 256;
    const int gb_rows64 = (N + 63) / 64;      // 782
    const int gb_edges  = (E + TB - 1) / TB;
    const int gb_nodes  = (N + 3) / 4;
    const int nsb       = (N + 1023) / 1024;  // 49 scan blocks

    // ---- prepack W fragments ----
    prepack_w<256, 128, 16><<<(9 * 8 * 64 + TB - 1) / TB, TB, 0, stream>>>(W0, al0, ar0, Wp0);
    prepack_w<128, 128, 16><<<(9 * 4 * 64 + TB - 1) / TB, TB, 0, stream>>>(W1, al1, ar1, Wp1);
    prepack_w<128, 64, 64><<<(5 * 4 * 64 + TB - 1) / TB, TB, 0, stream>>>(W2, al2, ar2, Wp2);

    // ---- CSR build (shared by all 3 layers) ----
    zero_ints<<<(2 * N + TB - 1) / TB, TB, 0, stream>>>(deg, 2 * N);
    hist_deg<<<gb_edges, TB, 0, stream>>>(dst, deg);
    scan_partials<<<nsb, 1024, 0, stream>>>(deg, btot, N);
    scan_btot<<<1, 64, 0, stream>>>(btot, nsb);
    scan_final<<<nsb, 1024, 0, stream>>>(deg, btot, offs, N);
    build_csr<<<gb_edges, TB, 0, stream>>>(src, dst, offs, cursor, csr_src);

    // ---- layer 0: 256 -> 8 heads x 16, ELU ----
    gemm_attn_mfma<256, 128, 16><<<gb_rows64, 256, 0, stream>>>(x, Wp0, feat, elb, erb, N);
    node_flash_agg<8, 16, true><<<gb_nodes, 256, 0, stream>>>(
        offs, csr_src, elb, erb, feat, b0, hbuf, N);

    // ---- layer 1: 128 -> 8 heads x 16, ELU ----
    gemm_attn_mfma<128, 128, 16><<<gb_rows64, 256, 0, stream>>>(hbuf, Wp1, feat, elb, erb, N);
    node_flash_agg<8, 16, true><<<gb_nodes, 256, 0, stream>>>(
        offs, csr_src, elb, erb, feat, b1, hbuf, N);

    // ---- layer 2: 128 -> 1 head x 64, no act ----
    gemm_attn_mfma<128, 64, 64><<<gb_rows64, 256, 0, stream>>>(hbuf, Wp2, feat, elb, erb, N);
    node_flash_agg<1, 64, false><<<gb_nodes, 256, 0, stream>>>(
        offs, csr_src, elb, erb, feat, b2, out, N);
}